// Round 11
// baseline (706.144 us; speedup 1.0000x reference)
//
#include <hip/hip_runtime.h>

// DGCNN on MI355X — round 11: k4 fused into k3 (g never leaves the block).
// R10 post-mortem: compiler sank the register prefetch (VGPR=88 < braw+acc);
// k3 stuck ~240us, k4 ~60us with a 102MB g round-trip between them. Fusion:
// after the pair loop each wave holds g for its 4 nodes (all 8 nt) -> save in
// 32 regs, barrier, g -> ashare (A-frag layout, k4-verified formulas), W5 GEMM
// (wave w: nt 2w,2w+1; frags from L2), t1 -> ashare frag kc=w (wave-exclusive),
// W6 GEMM (waves 0-2), store out. 5 barriers/block, -k4 dispatch, -102MB HBM.
//   concat(a, b-a) @ W + bias = a @ (Wt-Wb) + b @ Wb + bias
//   conv2 gathers h1 with NODE ids -> only h1[0:N] rows needed

#define NN 100000
#define KNB 16
#define EE (NN * KNB)

// weight fragment bases (units of 512 ushorts = one 64-lane x 8-bf16 frag)
#define W2F 0     // W2  [64][64]   : 2 kc x 4 nt  = 8
#define W3F 8     // W3X [64][256]  : 2 kc x 16 nt = 32  (cols 0-127: W3t-W3b, 128-255: W3b)
#define W4F 40    // W4  [128][128] : 4 kc x 8 nt  = 32
#define W5F 72    // W5  [128][128] : 4 kc x 8 nt  = 32
#define W6F 104   // W6  [128][48p] : 4 kc x 3 nt  = 12
#define NFRAG 116

typedef float floatx4 __attribute__((ext_vector_type(4)));
typedef __bf16 bf16x8 __attribute__((ext_vector_type(8)));

static __device__ __forceinline__ unsigned f2bf_rne_u(float f) {
    unsigned u = __float_as_uint(f);
    return (u + 0x7FFFu + ((u >> 16) & 1u)) >> 16;
}
static __device__ __forceinline__ float bfu2f(unsigned h) {
    return __uint_as_float(h << 16);
}

// split a pair of fp32 into packed bf16 hi (truncate) + bf16 lo (RNE of exact
// residual). hp = {lo16: a_hi, hi16: b_hi}; one v_perm_b32 per pack.
static __device__ __forceinline__ void split_pack2(float a, float b,
                                                   unsigned& hp, unsigned& lp) {
    unsigned ua = __float_as_uint(a), ub = __float_as_uint(b);
    hp = __builtin_amdgcn_perm(ub, ua, 0x07060302u);        // [b.b3 b.b2 a.b3 a.b2]
    float ra = a - __uint_as_float(ua & 0xFFFF0000u);       // exact residual
    float rb = b - __uint_as_float(ub & 0xFFFF0000u);
    unsigned la = __float_as_uint(ra), lb = __float_as_uint(rb);
    la = la + 0x7FFFu + ((la >> 16) & 1u);                  // RNE round point
    lb = lb + 0x7FFFu + ((lb >> 16) & 1u);
    lp = __builtin_amdgcn_perm(lb, la, 0x07060302u);
}

// split 8 fp32 -> bf16x8 hi + bf16x8 lo
static __device__ __forceinline__ void split8(float4 f0, float4 f1,
                                              bf16x8& ah, bf16x8& al) {
    unsigned hd[4], ld[4];
    split_pack2(f0.x, f0.y, hd[0], ld[0]);
    split_pack2(f0.z, f0.w, hd[1], ld[1]);
    split_pack2(f1.x, f1.y, hd[2], ld[2]);
    split_pack2(f1.z, f1.w, hd[3], ld[3]);
    uint4 H = {hd[0], hd[1], hd[2], hd[3]};
    uint4 L = {ld[0], ld[1], ld[2], ld[3]};
    ah = __builtin_bit_cast(bf16x8, H);
    al = __builtin_bit_cast(bf16x8, L);
}

// ---------------- KW: pre-split all weights into frag-ordered bf16 hi/lo ------
// Frag (kc,nt): lane l holds W[kc*32 + (l>>4)*8 + j][nt*16 + (l&15)], j=0..7.
__global__ __launch_bounds__(256) void kw_kernel(
    const float* __restrict__ W2, const float* __restrict__ W3,
    const float* __restrict__ W4, const float* __restrict__ W5,
    const float* __restrict__ W6,
    unsigned short* __restrict__ WH, unsigned short* __restrict__ WL)
{
    int d = blockIdx.x * 256 + threadIdx.x;
    if (d >= NFRAG * 64) return;
    int f = d >> 6, l = d & 63, c = l & 15, q = l >> 4;
    float v[8];
    if (f < W3F) {                    // W2 [64][64]
        int fx = f - W2F, kc = fx >> 2, nt = fx & 3;
        int k0 = kc * 32 + q * 8, n = nt * 16 + c;
#pragma unroll
        for (int j = 0; j < 8; ++j) v[j] = W2[(k0 + j) * 64 + n];
    } else if (f < W4F) {             // W3X [64][256]
        int fx = f - W3F, kc = fx >> 4, nt = fx & 15;
        int k0 = kc * 32 + q * 8, n = nt * 16 + c;
#pragma unroll
        for (int j = 0; j < 8; ++j) {
            int k = k0 + j;
            v[j] = (n < 128) ? (W3[k * 128 + n] - W3[(64 + k) * 128 + n])
                             : W3[(64 + k) * 128 + (n - 128)];
        }
    } else if (f < W5F) {             // W4 [128][128]
        int fx = f - W4F, kc = fx >> 3, nt = fx & 7;
        int k0 = kc * 32 + q * 8, n = nt * 16 + c;
#pragma unroll
        for (int j = 0; j < 8; ++j) v[j] = W4[(k0 + j) * 128 + n];
    } else if (f < W6F) {             // W5 [128][128]
        int fx = f - W5F, kc = fx >> 3, nt = fx & 7;
        int k0 = kc * 32 + q * 8, n = nt * 16 + c;
#pragma unroll
        for (int j = 0; j < 8; ++j) v[j] = W5[(k0 + j) * 128 + n];
    } else {                          // W6 [128][40] padded to 48
        int fx = f - W6F, kc = fx / 3, nt = fx % 3;
        int k0 = kc * 32 + q * 8, n = nt * 16 + c;
#pragma unroll
        for (int j = 0; j < 8; ++j)
            v[j] = (n < 40) ? W6[(k0 + j) * 40 + n] : 0.0f;
    }
    unsigned hs[8], ls[8];
#pragma unroll
    for (int j = 0; j < 8; ++j) {
        unsigned h = f2bf_rne_u(v[j]);
        float r = v[j] - bfu2f(h);
        hs[j] = h;
        ls[j] = f2bf_rne_u(r);
    }
    uint4 H, L;
    H.x = hs[0] | (hs[1] << 16); H.y = hs[2] | (hs[3] << 16);
    H.z = hs[4] | (hs[5] << 16); H.w = hs[6] | (hs[7] << 16);
    L.x = ls[0] | (ls[1] << 16); L.y = ls[2] | (ls[3] << 16);
    L.z = ls[4] | (ls[5] << 16); L.w = ls[6] | (ls[7] << 16);
    *(uint4*)(WH + (size_t)d * 8) = H;
    *(uint4*)(WL + (size_t)d * 8) = L;
}

// ---------------- K1: A1 = x@(W1t-W1b)+b1, B1 = x@W1b ----------------
__global__ __launch_bounds__(256) void k1_kernel(
    const float* __restrict__ x, const float* __restrict__ W1,
    const float* __restrict__ b1, float* __restrict__ A1, float* __restrict__ B1)
{
    int gid = blockIdx.x * 256 + threadIdx.x;
    int n = gid >> 6;
    int j = gid & 63;
    const float* xr = x + n * 16;
    float acc_a = b1[j];
    float acc_b = 0.0f;
#pragma unroll
    for (int k = 0; k < 16; ++k) {
        float xv = xr[k];
        float wt = W1[k * 64 + j];
        float wb = W1[(16 + k) * 64 + j];
        acc_a = fmaf(xv, wt - wb, acc_a);
        acc_b = fmaf(xv, wb, acc_b);
    }
    A1[n * 64 + j] = acc_a;
    B1[n * 64 + j] = acc_b;
}

// ---------------- K2 (MFMA): 64 rows/block --------------------
__global__ __launch_bounds__(256) void k2_kernel(
    const int* __restrict__ col,
    const float* __restrict__ A1, const float* __restrict__ B1,
    const unsigned short* __restrict__ WH, const unsigned short* __restrict__ WL,
    const float* __restrict__ b2, const float* __restrict__ b3,
    float* __restrict__ A3, float* __restrict__ B3)
{
    __shared__ __align__(16) float tF[8 * 512];   // 16 KB, frag-contig fp32
    __shared__ __align__(16) float hF[8 * 512];   // 16 KB
    const int t = threadIdx.x;
    const int i0 = blockIdx.x * 64;

    // phase A: t[row] = relu(A1[i>>4] + B1[col[i]]) -> tF frag layout
    {
        const int row = t & 63, part = t >> 6;
        int i = i0 + row;                 // tail reads valid (i < EE), stores guarded
        int nn = i >> 4;
        int ci = col[i];
        const float* ar = A1 + (size_t)nn * 64 + part * 16;
        const float* br = B1 + (size_t)ci * 64 + part * 16;
        int mt = row >> 4, m = row & 15, kc = part >> 1;
        float* base = tF + (mt * 2 + kc) * 512 + m * 8;
#pragma unroll
        for (int h = 0; h < 2; ++h) {
            int qq = (part & 1) * 2 + h;
            float4 a0 = *(const float4*)(ar + h * 8);
            float4 b0 = *(const float4*)(br + h * 8);
            float4 a1 = *(const float4*)(ar + h * 8 + 4);
            float4 b1v = *(const float4*)(br + h * 8 + 4);
            float4 r0, r1;
            r0.x = fmaxf(a0.x + b0.x, 0.0f); r0.y = fmaxf(a0.y + b0.y, 0.0f);
            r0.z = fmaxf(a0.z + b0.z, 0.0f); r0.w = fmaxf(a0.w + b0.w, 0.0f);
            r1.x = fmaxf(a1.x + b1v.x, 0.0f); r1.y = fmaxf(a1.y + b1v.y, 0.0f);
            r1.z = fmaxf(a1.z + b1v.z, 0.0f); r1.w = fmaxf(a1.w + b1v.w, 0.0f);
            *(float4*)(base + qq * 128) = r0;
            *(float4*)(base + qq * 128 + 4) = r1;
        }
    }
    __syncthreads();

    const int w = __builtin_amdgcn_readfirstlane(t >> 6);   // wave = m-tile
    const int lane = t & 63;

    // GEMM1: h-tile rows w*16..+15; acc1[nt=0..3]
    floatx4 acc1[4];
#pragma unroll
    for (int nt = 0; nt < 4; ++nt) acc1[nt] = (floatx4){0.f, 0.f, 0.f, 0.f};
#pragma unroll
    for (int kc = 0; kc < 2; ++kc) {
        const float* ap = tF + (w * 2 + kc) * 512 + lane * 8;
        bf16x8 ah, al;
        split8(*(const float4*)ap, *(const float4*)(ap + 4), ah, al);
#pragma unroll
        for (int nt = 0; nt < 4; ++nt) {
            size_t fb = (size_t)(W2F + kc * 4 + nt) * 512 + lane * 8;
            bf16x8 bh = __builtin_bit_cast(bf16x8, *(const uint4*)(WH + fb));
            bf16x8 bl = __builtin_bit_cast(bf16x8, *(const uint4*)(WL + fb));
            acc1[nt] = __builtin_amdgcn_mfma_f32_16x16x32_bf16(ah, bh, acc1[nt], 0, 0, 0);
            acc1[nt] = __builtin_amdgcn_mfma_f32_16x16x32_bf16(ah, bl, acc1[nt], 0, 0, 0);
            acc1[nt] = __builtin_amdgcn_mfma_f32_16x16x32_bf16(al, bh, acc1[nt], 0, 0, 0);
        }
    }
    // h = relu(acc1 + b2) -> hF frag layout (wave-local rows -> no barrier)
    {
        const int qq = lane >> 4, cc = lane & 15;
#pragma unroll
        for (int nt = 0; nt < 4; ++nt) {
            float bv = b2[nt * 16 + cc];
            int colIdx = nt * 16 + cc;
            int kc2 = colIdx >> 5, q2 = (colIdx >> 3) & 3, jj = cc & 7;
            float* dst = hF + (w * 2 + kc2) * 512 + q2 * 128 + jj;
#pragma unroll
            for (int r = 0; r < 4; ++r)
                dst[(qq * 4 + r) * 8] = fmaxf(acc1[nt][r] + bv, 0.0f);
        }
    }
    // GEMM2: [16 x 64] @ W3X[64 x 256]; acc2[nt=0..15]
    floatx4 acc2[16];
#pragma unroll
    for (int nt = 0; nt < 16; ++nt) acc2[nt] = (floatx4){0.f, 0.f, 0.f, 0.f};
#pragma unroll
    for (int kc = 0; kc < 2; ++kc) {
        const float* ap = hF + (w * 2 + kc) * 512 + lane * 8;
        bf16x8 ah, al;
        split8(*(const float4*)ap, *(const float4*)(ap + 4), ah, al);
#pragma unroll
        for (int nt = 0; nt < 16; ++nt) {
            size_t fb = (size_t)(W3F + kc * 16 + nt) * 512 + lane * 8;
            bf16x8 bh = __builtin_bit_cast(bf16x8, *(const uint4*)(WH + fb));
            bf16x8 bl = __builtin_bit_cast(bf16x8, *(const uint4*)(WL + fb));
            acc2[nt] = __builtin_amdgcn_mfma_f32_16x16x32_bf16(ah, bh, acc2[nt], 0, 0, 0);
            acc2[nt] = __builtin_amdgcn_mfma_f32_16x16x32_bf16(ah, bl, acc2[nt], 0, 0, 0);
            acc2[nt] = __builtin_amdgcn_mfma_f32_16x16x32_bf16(al, bh, acc2[nt], 0, 0, 0);
        }
    }
    // store: cols 0-127 -> A3 (+b3), 128-255 -> B3
    {
        const int qq = lane >> 4, cc = lane & 15;
#pragma unroll
        for (int nt = 0; nt < 16; ++nt) {
            int n = nt * 16 + cc;
            float bv = (n < 128) ? b3[n] : 0.0f;
#pragma unroll
            for (int r = 0; r < 4; ++r) {
                int i = i0 + w * 16 + qq * 4 + r;
                if (i < NN) {
                    float vv = acc2[nt][r];
                    if (n < 128) A3[(size_t)i * 128 + n] = vv + bv;
                    else         B3[(size_t)i * 128 + (n - 128)] = vv;
                }
            }
        }
    }
}

// ---------------- K3 (fused): edge-GEMM + K-max + node MLP -> out -------------
// Block = 16 nodes, 4 waves. LDS: W4 hi/lo frags (64KB) + 8KB ashare
// (A3 rows, then g frags, then t1 frags). Pair loop identical to R10.
__global__ __launch_bounds__(256, 2) void k3_kernel(
    const int* __restrict__ col,
    const float* __restrict__ A3, const float* __restrict__ B3,
    const unsigned short* __restrict__ WH, const unsigned short* __restrict__ WL,
    const float* __restrict__ b4, const float* __restrict__ b5,
    const float* __restrict__ b6, float* __restrict__ out)
{
    __shared__ __align__(16) unsigned short wlds[32768];  // 64 KB: W4 H then L
    __shared__ __align__(16) float ashare[2048];          // 8 KB, multi-use
    const int t = threadIdx.x;
    const int lane = t & 63;
    const int w = t >> 6;
    const int m = lane & 15, q = lane >> 4;
    const int nodeB = blockIdx.x * 16;
    const int node0 = nodeB + w * 4;

    // prefetch pair0's B3 gather (issued before staging so it's in flight)
    float4 braw[16];
#pragma unroll
    for (int ng = 0; ng < 2; ++ng) {
        const int c = col[(node0 + ng) * KNB + m];
        const float* br = B3 + (size_t)c * 128 + q * 8;
#pragma unroll
        for (int kc = 0; kc < 4; ++kc) {
            braw[ng * 8 + kc * 2]     = *(const float4*)(br + kc * 32);
            braw[ng * 8 + kc * 2 + 1] = *(const float4*)(br + kc * 32 + 4);
        }
    }
    // stage A3 rows (8 KB) and W4 hi/lo frags (64 KB), coalesced
    {
        const float4* asrc = (const float4*)(A3 + (size_t)nodeB * 128);
        float4* adst = (float4*)ashare;
        adst[t]       = asrc[t];
        adst[t + 256] = asrc[t + 256];
        const uint4* hsrc = (const uint4*)(WH + (size_t)W4F * 512 * 8 / 8);
        const uint4* lsrc = (const uint4*)(WL + (size_t)W4F * 512);
        hsrc = (const uint4*)(WH + (size_t)W4F * 512);
        uint4* wdst = (uint4*)wlds;
#pragma unroll
        for (int i = 0; i < 8; ++i) wdst[t + i * 256]        = hsrc[t + i * 256];
#pragma unroll
        for (int i = 0; i < 8; ++i) wdst[2048 + t + i * 256] = lsrc[t + i * 256];
    }
    __syncthreads();

    float gsave[4][8];   // [node_local p*2+ng][nt], valid in lanes<16

#pragma unroll
    for (int p = 0; p < 2; ++p) {
        // split current pair: lane's A-frag = relu(A3[node]+B3[col]) hi/lo
        bf16x8 aH[2][4], aL[2][4];
#pragma unroll
        for (int ng = 0; ng < 2; ++ng) {
            const float* ar = ashare + (w * 4 + p * 2 + ng) * 128 + q * 8;
#pragma unroll
            for (int kc = 0; kc < 4; ++kc) {
                float4 b0 = braw[ng * 8 + kc * 2];
                float4 b1 = braw[ng * 8 + kc * 2 + 1];
                float4 a0 = *(const float4*)(ar + kc * 32);
                float4 a1 = *(const float4*)(ar + kc * 32 + 4);
                float v0 = fmaxf(a0.x + b0.x, 0.0f), v1 = fmaxf(a0.y + b0.y, 0.0f);
                float v2 = fmaxf(a0.z + b0.z, 0.0f), v3 = fmaxf(a0.w + b0.w, 0.0f);
                float v4 = fmaxf(a1.x + b1.x, 0.0f), v5 = fmaxf(a1.y + b1.y, 0.0f);
                float v6 = fmaxf(a1.z + b1.z, 0.0f), v7 = fmaxf(a1.w + b1.w, 0.0f);
                uint4 H, L;
                split_pack2(v0, v1, H.x, L.x);
                split_pack2(v2, v3, H.y, L.y);
                split_pack2(v4, v5, H.z, L.z);
                split_pack2(v6, v7, H.w, L.w);
                aH[ng][kc] = __builtin_bit_cast(bf16x8, H);
                aL[ng][kc] = __builtin_bit_cast(bf16x8, L);
            }
        }
        // issue next pair's gather NOW; lands during this pair's MFMA phase
        if (p == 0) {
#pragma unroll
            for (int ng = 0; ng < 2; ++ng) {
                const int c = col[(node0 + 2 + ng) * KNB + m];
                const float* br = B3 + (size_t)c * 128 + q * 8;
#pragma unroll
                for (int kc = 0; kc < 4; ++kc) {
                    braw[ng * 8 + kc * 2]     = *(const float4*)(br + kc * 32);
                    braw[ng * 8 + kc * 2 + 1] = *(const float4*)(br + kc * 32 + 4);
                }
            }
        }
        // MFMA: all 8 n-tiles for both nodes; bh/bl amortized over 6 MFMAs
        floatx4 acc[2][8];
#pragma unroll
        for (int ng = 0; ng < 2; ++ng)
#pragma unroll
            for (int nt = 0; nt < 8; ++nt)
                acc[ng][nt] = (floatx4){0.0f, 0.0f, 0.0f, 0.0f};
#pragma unroll
        for (int kc = 0; kc < 4; ++kc) {
#pragma unroll
            for (int nt = 0; nt < 8; ++nt) {
                const int f = kc * 8 + nt;
                bf16x8 bh = __builtin_bit_cast(bf16x8,
                    *(const uint4*)(wlds + f * 512 + lane * 8));
                bf16x8 bl = __builtin_bit_cast(bf16x8,
                    *(const uint4*)(wlds + 16384 + f * 512 + lane * 8));
#pragma unroll
                for (int ng = 0; ng < 2; ++ng) {
                    acc[ng][nt] = __builtin_amdgcn_mfma_f32_16x16x32_bf16(
                        aH[ng][kc], bh, acc[ng][nt], 0, 0, 0);
                    acc[ng][nt] = __builtin_amdgcn_mfma_f32_16x16x32_bf16(
                        aH[ng][kc], bl, acc[ng][nt], 0, 0, 0);
                    acc[ng][nt] = __builtin_amdgcn_mfma_f32_16x16x32_bf16(
                        aL[ng][kc], bh, acc[ng][nt], 0, 0, 0);
                }
            }
        }
        // K-max in-register; save g = relu(max + b4) in registers
#pragma unroll
        for (int ng = 0; ng < 2; ++ng) {
#pragma unroll
            for (int nt = 0; nt < 8; ++nt) {
                floatx4 a = acc[ng][nt];
                float mm = fmaxf(fmaxf(a[0], a[1]), fmaxf(a[2], a[3]));
                mm = fmaxf(mm, __shfl_xor(mm, 16));
                mm = fmaxf(mm, __shfl_xor(mm, 32));
                int ccol = nt * 16 + (lane & 15);
                gsave[p * 2 + ng][nt] = fmaxf(mm + b4[ccol], 0.0f);
            }
        }
    }

    // ---- fused node MLP: out = relu(g@W5+b5) @ W6 + b6 ----
    __syncthreads();                    // all waves done reading ashare A3 rows
    if (lane < 16) {                    // g -> ashare in A-frag layout (m-tile=16)
        const int cc = lane;
#pragma unroll
        for (int pg = 0; pg < 4; ++pg) {
            const int mloc = w * 4 + pg;
#pragma unroll
            for (int nt = 0; nt < 8; ++nt) {
                int colI = nt * 16 + cc;
                int kc2 = colI >> 5, q2 = (colI >> 3) & 3, jj = colI & 7;
                ashare[kc2 * 512 + q2 * 128 + mloc * 8 + jj] = gsave[pg][nt];
            }
        }
    }
    __syncthreads();
    // W5 GEMM: wave w -> nt {2w, 2w+1}; W5 frags streamed from L2
    floatx4 acc5[2];
    acc5[0] = (floatx4){0.f, 0.f, 0.f, 0.f};
    acc5[1] = (floatx4){0.f, 0.f, 0.f, 0.f};
#pragma unroll
    for (int kc = 0; kc < 4; ++kc) {
        const float* ap = ashare + kc * 512 + lane * 8;
        bf16x8 ah, al;
        split8(*(const float4*)ap, *(const float4*)(ap + 4), ah, al);
#pragma unroll
        for (int ntl = 0; ntl < 2; ++ntl) {
            int nt = w * 2 + ntl;
            size_t fb = (size_t)(W5F + kc * 8 + nt) * 512 + lane * 8;
            bf16x8 bh = __builtin_bit_cast(bf16x8, *(const uint4*)(WH + fb));
            bf16x8 bl = __builtin_bit_cast(bf16x8, *(const uint4*)(WL + fb));
            acc5[ntl] = __builtin_amdgcn_mfma_f32_16x16x32_bf16(ah, bh, acc5[ntl], 0, 0, 0);
            acc5[ntl] = __builtin_amdgcn_mfma_f32_16x16x32_bf16(ah, bl, acc5[ntl], 0, 0, 0);
            acc5[ntl] = __builtin_amdgcn_mfma_f32_16x16x32_bf16(al, bh, acc5[ntl], 0, 0, 0);
        }
    }
    __syncthreads();                    // all W5 reads of ashare done
    {   // t1 = relu(acc5 + b5) -> ashare frag kc=w (wave-exclusive region)
        const int qq = lane >> 4, cc = lane & 15;
#pragma unroll
        for (int ntl = 0; ntl < 2; ++ntl) {
            int nt = w * 2 + ntl;
            float bv = b5[nt * 16 + cc];
            int colI = nt * 16 + cc;
            int kc2 = colI >> 5, q2 = (colI >> 3) & 3, jj = cc & 7;
            float* dst = ashare + kc2 * 512 + q2 * 128 + jj;
#pragma unroll
            for (int r = 0; r < 4; ++r)
                dst[(qq * 4 + r) * 8] = fmaxf(acc5[ntl][r] + bv, 0.0f);
        }
    }
    __syncthreads();
    // W6 GEMM: waves 0..2, nt = w; store out
    if (w < 3) {
        floatx4 acc6 = (floatx4){0.f, 0.f, 0.f, 0.f};
#pragma unroll
        for (int kc = 0; kc < 4; ++kc) {
            const float* ap = ashare + kc * 512 + lane * 8;
            bf16x8 ah, al;
            split8(*(const float4*)ap, *(const float4*)(ap + 4), ah, al);
            size_t fb = (size_t)(W6F + kc * 3 + w) * 512 + lane * 8;
            bf16x8 bh = __builtin_bit_cast(bf16x8, *(const uint4*)(WH + fb));
            bf16x8 bl = __builtin_bit_cast(bf16x8, *(const uint4*)(WL + fb));
            acc6 = __builtin_amdgcn_mfma_f32_16x16x32_bf16(ah, bh, acc6, 0, 0, 0);
            acc6 = __builtin_amdgcn_mfma_f32_16x16x32_bf16(ah, bl, acc6, 0, 0, 0);
            acc6 = __builtin_amdgcn_mfma_f32_16x16x32_bf16(al, bh, acc6, 0, 0, 0);
        }
        const int qq = lane >> 4, cc = lane & 15;
        int n = w * 16 + cc;
        if (n < 40) {
            float bv = b6[n];
#pragma unroll
            for (int r = 0; r < 4; ++r)
                out[(size_t)(nodeB + qq * 4 + r) * 40 + n] = acc6[r] + bv;
        }
    }
}

extern "C" void kernel_launch(void* const* d_in, const int* in_sizes, int n_in,
                              void* d_out, int out_size, void* d_ws, size_t ws_size,
                              hipStream_t stream)
{
    const float* x  = (const float*)d_in[0];
    const int* ei   = (const int*)d_in[1];
    const int* col  = ei + EE;
    const float* W1 = (const float*)d_in[2];
    const float* b1 = (const float*)d_in[3];
    const float* W2 = (const float*)d_in[4];
    const float* b2 = (const float*)d_in[5];
    const float* W3 = (const float*)d_in[6];
    const float* b3 = (const float*)d_in[7];
    const float* W4 = (const float*)d_in[8];
    const float* b4 = (const float*)d_in[9];
    const float* W5 = (const float*)d_in[10];
    const float* b5 = (const float*)d_in[11];
    const float* W6 = (const float*)d_in[12];
    const float* b6 = (const float*)d_in[13];
    float* out = (float*)d_out;

    float* A1 = (float*)d_ws;                    // [N,64]
    float* B1 = A1 + (size_t)NN * 64;            // [N,64]
    float* A3 = B1 + (size_t)NN * 64;            // [N,128]
    float* B3 = A3 + (size_t)NN * 128;           // [N,128]
    unsigned short* WH = (unsigned short*)(B3 + (size_t)NN * 128);  // [116*512]
    unsigned short* WL = WH + NFRAG * 512;

    kw_kernel<<<(NFRAG * 64 + 255) / 256, 256, 0, stream>>>(W2, W3, W4, W5, W6, WH, WL);
    k1_kernel<<<NN * 64 / 256, 256, 0, stream>>>(x, W1, b1, A1, B1);
    k2_kernel<<<(NN + 63) / 64, 256, 0, stream>>>(col, A1, B1, WH, WL, b2, b3, A3, B3);
    k3_kernel<<<NN / 16, 256, 0, stream>>>(col, A3, B3, WH, WL, b4, b5, b6, out);
}

// Round 12
// 451.331 us; speedup vs baseline: 1.5646x; 1.5646x over previous
//
#include <hip/hip_runtime.h>

// DGCNN on MI355X — round 12: R11 fusion retried with g routed through LDS.
// R11 post-mortem: gsave[4][8] carried across the pair loop pushed peak live
// regs >190 -> compiler spilled (WRITE 1.14GB). Rule (R8, R11): values that
// bridge the high-pressure pair loop go to LDS, not registers. Now: after each
// pair's K-max, lanes<16 write g directly into an 8KB gshare (frag layout);
// epilogue (W5/W6 MLP, R11-verified formulas) reads gshare, writes t1 into
// ashare (dead after pair loop), stores out. LDS 80KB -> 2 blocks/CU.
//   concat(a, b-a) @ W + bias = a @ (Wt-Wb) + b @ Wb + bias
//   conv2 gathers h1 with NODE ids -> only h1[0:N] rows needed

#define NN 100000
#define KNB 16
#define EE (NN * KNB)

// weight fragment bases (units of 512 ushorts = one 64-lane x 8-bf16 frag)
#define W2F 0     // W2  [64][64]   : 2 kc x 4 nt  = 8
#define W3F 8     // W3X [64][256]  : 2 kc x 16 nt = 32  (cols 0-127: W3t-W3b, 128-255: W3b)
#define W4F 40    // W4  [128][128] : 4 kc x 8 nt  = 32
#define W5F 72    // W5  [128][128] : 4 kc x 8 nt  = 32
#define W6F 104   // W6  [128][48p] : 4 kc x 3 nt  = 12
#define NFRAG 116

typedef float floatx4 __attribute__((ext_vector_type(4)));
typedef __bf16 bf16x8 __attribute__((ext_vector_type(8)));

static __device__ __forceinline__ unsigned f2bf_rne_u(float f) {
    unsigned u = __float_as_uint(f);
    return (u + 0x7FFFu + ((u >> 16) & 1u)) >> 16;
}
static __device__ __forceinline__ float bfu2f(unsigned h) {
    return __uint_as_float(h << 16);
}

// split a pair of fp32 into packed bf16 hi (truncate) + bf16 lo (RNE of exact
// residual). hp = {lo16: a_hi, hi16: b_hi}; one v_perm_b32 per pack.
static __device__ __forceinline__ void split_pack2(float a, float b,
                                                   unsigned& hp, unsigned& lp) {
    unsigned ua = __float_as_uint(a), ub = __float_as_uint(b);
    hp = __builtin_amdgcn_perm(ub, ua, 0x07060302u);        // [b.b3 b.b2 a.b3 a.b2]
    float ra = a - __uint_as_float(ua & 0xFFFF0000u);       // exact residual
    float rb = b - __uint_as_float(ub & 0xFFFF0000u);
    unsigned la = __float_as_uint(ra), lb = __float_as_uint(rb);
    la = la + 0x7FFFu + ((la >> 16) & 1u);                  // RNE round point
    lb = lb + 0x7FFFu + ((lb >> 16) & 1u);
    lp = __builtin_amdgcn_perm(lb, la, 0x07060302u);
}

// split 8 fp32 -> bf16x8 hi + bf16x8 lo
static __device__ __forceinline__ void split8(float4 f0, float4 f1,
                                              bf16x8& ah, bf16x8& al) {
    unsigned hd[4], ld[4];
    split_pack2(f0.x, f0.y, hd[0], ld[0]);
    split_pack2(f0.z, f0.w, hd[1], ld[1]);
    split_pack2(f1.x, f1.y, hd[2], ld[2]);
    split_pack2(f1.z, f1.w, hd[3], ld[3]);
    uint4 H = {hd[0], hd[1], hd[2], hd[3]};
    uint4 L = {ld[0], ld[1], ld[2], ld[3]};
    ah = __builtin_bit_cast(bf16x8, H);
    al = __builtin_bit_cast(bf16x8, L);
}

// ---------------- KW: pre-split all weights into frag-ordered bf16 hi/lo ------
// Frag (kc,nt): lane l holds W[kc*32 + (l>>4)*8 + j][nt*16 + (l&15)], j=0..7.
__global__ __launch_bounds__(256) void kw_kernel(
    const float* __restrict__ W2, const float* __restrict__ W3,
    const float* __restrict__ W4, const float* __restrict__ W5,
    const float* __restrict__ W6,
    unsigned short* __restrict__ WH, unsigned short* __restrict__ WL)
{
    int d = blockIdx.x * 256 + threadIdx.x;
    if (d >= NFRAG * 64) return;
    int f = d >> 6, l = d & 63, c = l & 15, q = l >> 4;
    float v[8];
    if (f < W3F) {                    // W2 [64][64]
        int fx = f - W2F, kc = fx >> 2, nt = fx & 3;
        int k0 = kc * 32 + q * 8, n = nt * 16 + c;
#pragma unroll
        for (int j = 0; j < 8; ++j) v[j] = W2[(k0 + j) * 64 + n];
    } else if (f < W4F) {             // W3X [64][256]
        int fx = f - W3F, kc = fx >> 4, nt = fx & 15;
        int k0 = kc * 32 + q * 8, n = nt * 16 + c;
#pragma unroll
        for (int j = 0; j < 8; ++j) {
            int k = k0 + j;
            v[j] = (n < 128) ? (W3[k * 128 + n] - W3[(64 + k) * 128 + n])
                             : W3[(64 + k) * 128 + (n - 128)];
        }
    } else if (f < W5F) {             // W4 [128][128]
        int fx = f - W4F, kc = fx >> 3, nt = fx & 7;
        int k0 = kc * 32 + q * 8, n = nt * 16 + c;
#pragma unroll
        for (int j = 0; j < 8; ++j) v[j] = W4[(k0 + j) * 128 + n];
    } else if (f < W6F) {             // W5 [128][128]
        int fx = f - W5F, kc = fx >> 3, nt = fx & 7;
        int k0 = kc * 32 + q * 8, n = nt * 16 + c;
#pragma unroll
        for (int j = 0; j < 8; ++j) v[j] = W5[(k0 + j) * 128 + n];
    } else {                          // W6 [128][40] padded to 48
        int fx = f - W6F, kc = fx / 3, nt = fx % 3;
        int k0 = kc * 32 + q * 8, n = nt * 16 + c;
#pragma unroll
        for (int j = 0; j < 8; ++j)
            v[j] = (n < 40) ? W6[(k0 + j) * 40 + n] : 0.0f;
    }
    unsigned hs[8], ls[8];
#pragma unroll
    for (int j = 0; j < 8; ++j) {
        unsigned h = f2bf_rne_u(v[j]);
        float r = v[j] - bfu2f(h);
        hs[j] = h;
        ls[j] = f2bf_rne_u(r);
    }
    uint4 H, L;
    H.x = hs[0] | (hs[1] << 16); H.y = hs[2] | (hs[3] << 16);
    H.z = hs[4] | (hs[5] << 16); H.w = hs[6] | (hs[7] << 16);
    L.x = ls[0] | (ls[1] << 16); L.y = ls[2] | (ls[3] << 16);
    L.z = ls[4] | (ls[5] << 16); L.w = ls[6] | (ls[7] << 16);
    *(uint4*)(WH + (size_t)d * 8) = H;
    *(uint4*)(WL + (size_t)d * 8) = L;
}

// ---------------- K1: A1 = x@(W1t-W1b)+b1, B1 = x@W1b ----------------
__global__ __launch_bounds__(256) void k1_kernel(
    const float* __restrict__ x, const float* __restrict__ W1,
    const float* __restrict__ b1, float* __restrict__ A1, float* __restrict__ B1)
{
    int gid = blockIdx.x * 256 + threadIdx.x;
    int n = gid >> 6;
    int j = gid & 63;
    const float* xr = x + n * 16;
    float acc_a = b1[j];
    float acc_b = 0.0f;
#pragma unroll
    for (int k = 0; k < 16; ++k) {
        float xv = xr[k];
        float wt = W1[k * 64 + j];
        float wb = W1[(16 + k) * 64 + j];
        acc_a = fmaf(xv, wt - wb, acc_a);
        acc_b = fmaf(xv, wb, acc_b);
    }
    A1[n * 64 + j] = acc_a;
    B1[n * 64 + j] = acc_b;
}

// ---------------- K2 (MFMA): 64 rows/block --------------------
__global__ __launch_bounds__(256) void k2_kernel(
    const int* __restrict__ col,
    const float* __restrict__ A1, const float* __restrict__ B1,
    const unsigned short* __restrict__ WH, const unsigned short* __restrict__ WL,
    const float* __restrict__ b2, const float* __restrict__ b3,
    float* __restrict__ A3, float* __restrict__ B3)
{
    __shared__ __align__(16) float tF[8 * 512];   // 16 KB, frag-contig fp32
    __shared__ __align__(16) float hF[8 * 512];   // 16 KB
    const int t = threadIdx.x;
    const int i0 = blockIdx.x * 64;

    // phase A: t[row] = relu(A1[i>>4] + B1[col[i]]) -> tF frag layout
    {
        const int row = t & 63, part = t >> 6;
        int i = i0 + row;                 // tail reads valid (i < EE), stores guarded
        int nn = i >> 4;
        int ci = col[i];
        const float* ar = A1 + (size_t)nn * 64 + part * 16;
        const float* br = B1 + (size_t)ci * 64 + part * 16;
        int mt = row >> 4, m = row & 15, kc = part >> 1;
        float* base = tF + (mt * 2 + kc) * 512 + m * 8;
#pragma unroll
        for (int h = 0; h < 2; ++h) {
            int qq = (part & 1) * 2 + h;
            float4 a0 = *(const float4*)(ar + h * 8);
            float4 b0 = *(const float4*)(br + h * 8);
            float4 a1 = *(const float4*)(ar + h * 8 + 4);
            float4 b1v = *(const float4*)(br + h * 8 + 4);
            float4 r0, r1;
            r0.x = fmaxf(a0.x + b0.x, 0.0f); r0.y = fmaxf(a0.y + b0.y, 0.0f);
            r0.z = fmaxf(a0.z + b0.z, 0.0f); r0.w = fmaxf(a0.w + b0.w, 0.0f);
            r1.x = fmaxf(a1.x + b1v.x, 0.0f); r1.y = fmaxf(a1.y + b1v.y, 0.0f);
            r1.z = fmaxf(a1.z + b1v.z, 0.0f); r1.w = fmaxf(a1.w + b1v.w, 0.0f);
            *(float4*)(base + qq * 128) = r0;
            *(float4*)(base + qq * 128 + 4) = r1;
        }
    }
    __syncthreads();

    const int w = __builtin_amdgcn_readfirstlane(t >> 6);   // wave = m-tile
    const int lane = t & 63;

    // GEMM1: h-tile rows w*16..+15; acc1[nt=0..3]
    floatx4 acc1[4];
#pragma unroll
    for (int nt = 0; nt < 4; ++nt) acc1[nt] = (floatx4){0.f, 0.f, 0.f, 0.f};
#pragma unroll
    for (int kc = 0; kc < 2; ++kc) {
        const float* ap = tF + (w * 2 + kc) * 512 + lane * 8;
        bf16x8 ah, al;
        split8(*(const float4*)ap, *(const float4*)(ap + 4), ah, al);
#pragma unroll
        for (int nt = 0; nt < 4; ++nt) {
            size_t fb = (size_t)(W2F + kc * 4 + nt) * 512 + lane * 8;
            bf16x8 bh = __builtin_bit_cast(bf16x8, *(const uint4*)(WH + fb));
            bf16x8 bl = __builtin_bit_cast(bf16x8, *(const uint4*)(WL + fb));
            acc1[nt] = __builtin_amdgcn_mfma_f32_16x16x32_bf16(ah, bh, acc1[nt], 0, 0, 0);
            acc1[nt] = __builtin_amdgcn_mfma_f32_16x16x32_bf16(ah, bl, acc1[nt], 0, 0, 0);
            acc1[nt] = __builtin_amdgcn_mfma_f32_16x16x32_bf16(al, bh, acc1[nt], 0, 0, 0);
        }
    }
    // h = relu(acc1 + b2) -> hF frag layout (wave-local rows -> no barrier)
    {
        const int qq = lane >> 4, cc = lane & 15;
#pragma unroll
        for (int nt = 0; nt < 4; ++nt) {
            float bv = b2[nt * 16 + cc];
            int colIdx = nt * 16 + cc;
            int kc2 = colIdx >> 5, q2 = (colIdx >> 3) & 3, jj = cc & 7;
            float* dst = hF + (w * 2 + kc2) * 512 + q2 * 128 + jj;
#pragma unroll
            for (int r = 0; r < 4; ++r)
                dst[(qq * 4 + r) * 8] = fmaxf(acc1[nt][r] + bv, 0.0f);
        }
    }
    // GEMM2: [16 x 64] @ W3X[64 x 256]; acc2[nt=0..15]
    floatx4 acc2[16];
#pragma unroll
    for (int nt = 0; nt < 16; ++nt) acc2[nt] = (floatx4){0.f, 0.f, 0.f, 0.f};
#pragma unroll
    for (int kc = 0; kc < 2; ++kc) {
        const float* ap = hF + (w * 2 + kc) * 512 + lane * 8;
        bf16x8 ah, al;
        split8(*(const float4*)ap, *(const float4*)(ap + 4), ah, al);
#pragma unroll
        for (int nt = 0; nt < 16; ++nt) {
            size_t fb = (size_t)(W3F + kc * 16 + nt) * 512 + lane * 8;
            bf16x8 bh = __builtin_bit_cast(bf16x8, *(const uint4*)(WH + fb));
            bf16x8 bl = __builtin_bit_cast(bf16x8, *(const uint4*)(WL + fb));
            acc2[nt] = __builtin_amdgcn_mfma_f32_16x16x32_bf16(ah, bh, acc2[nt], 0, 0, 0);
            acc2[nt] = __builtin_amdgcn_mfma_f32_16x16x32_bf16(ah, bl, acc2[nt], 0, 0, 0);
            acc2[nt] = __builtin_amdgcn_mfma_f32_16x16x32_bf16(al, bh, acc2[nt], 0, 0, 0);
        }
    }
    // store: cols 0-127 -> A3 (+b3), 128-255 -> B3
    {
        const int qq = lane >> 4, cc = lane & 15;
#pragma unroll
        for (int nt = 0; nt < 16; ++nt) {
            int n = nt * 16 + cc;
            float bv = (n < 128) ? b3[n] : 0.0f;
#pragma unroll
            for (int r = 0; r < 4; ++r) {
                int i = i0 + w * 16 + qq * 4 + r;
                if (i < NN) {
                    float vv = acc2[nt][r];
                    if (n < 128) A3[(size_t)i * 128 + n] = vv + bv;
                    else         B3[(size_t)i * 128 + (n - 128)] = vv;
                }
            }
        }
    }
}

// ---------------- K3 (fused): edge-GEMM + K-max -> gshare -> node MLP -> out --
// Block = 16 nodes, 4 waves. LDS: W4 frags 64KB + ashare 8KB + gshare 8KB.
// Pair loop identical to R10; g written straight to LDS (no register bridge).
__global__ __launch_bounds__(256, 2) void k3_kernel(
    const int* __restrict__ col,
    const float* __restrict__ A3, const float* __restrict__ B3,
    const unsigned short* __restrict__ WH, const unsigned short* __restrict__ WL,
    const float* __restrict__ b4, const float* __restrict__ b5,
    const float* __restrict__ b6, float* __restrict__ out)
{
    __shared__ __align__(16) unsigned short wlds[32768];  // 64 KB: W4 H then L
    __shared__ __align__(16) float ashare[2048];          // 8 KB: A3 rows, then t1
    __shared__ __align__(16) float gshare[2048];          // 8 KB: g in A-frag layout
    const int t = threadIdx.x;
    const int lane = t & 63;
    const int w = t >> 6;
    const int m = lane & 15, q = lane >> 4;
    const int nodeB = blockIdx.x * 16;
    const int node0 = nodeB + w * 4;

    // prefetch pair0's B3 gather (issued before staging so it's in flight)
    float4 braw[16];
#pragma unroll
    for (int ng = 0; ng < 2; ++ng) {
        const int c = col[(node0 + ng) * KNB + m];
        const float* br = B3 + (size_t)c * 128 + q * 8;
#pragma unroll
        for (int kc = 0; kc < 4; ++kc) {
            braw[ng * 8 + kc * 2]     = *(const float4*)(br + kc * 32);
            braw[ng * 8 + kc * 2 + 1] = *(const float4*)(br + kc * 32 + 4);
        }
    }
    // stage A3 rows (8 KB) and W4 hi/lo frags (64 KB), coalesced
    {
        const float4* asrc = (const float4*)(A3 + (size_t)nodeB * 128);
        float4* adst = (float4*)ashare;
        adst[t]       = asrc[t];
        adst[t + 256] = asrc[t + 256];
        const uint4* hsrc = (const uint4*)(WH + (size_t)W4F * 512);
        const uint4* lsrc = (const uint4*)(WL + (size_t)W4F * 512);
        uint4* wdst = (uint4*)wlds;
#pragma unroll
        for (int i = 0; i < 8; ++i) wdst[t + i * 256]        = hsrc[t + i * 256];
#pragma unroll
        for (int i = 0; i < 8; ++i) wdst[2048 + t + i * 256] = lsrc[t + i * 256];
    }
    __syncthreads();

#pragma unroll
    for (int p = 0; p < 2; ++p) {
        // split current pair: lane's A-frag = relu(A3[node]+B3[col]) hi/lo
        bf16x8 aH[2][4], aL[2][4];
#pragma unroll
        for (int ng = 0; ng < 2; ++ng) {
            const float* ar = ashare + (w * 4 + p * 2 + ng) * 128 + q * 8;
#pragma unroll
            for (int kc = 0; kc < 4; ++kc) {
                float4 b0 = braw[ng * 8 + kc * 2];
                float4 b1 = braw[ng * 8 + kc * 2 + 1];
                float4 a0 = *(const float4*)(ar + kc * 32);
                float4 a1 = *(const float4*)(ar + kc * 32 + 4);
                float v0 = fmaxf(a0.x + b0.x, 0.0f), v1 = fmaxf(a0.y + b0.y, 0.0f);
                float v2 = fmaxf(a0.z + b0.z, 0.0f), v3 = fmaxf(a0.w + b0.w, 0.0f);
                float v4 = fmaxf(a1.x + b1.x, 0.0f), v5 = fmaxf(a1.y + b1.y, 0.0f);
                float v6 = fmaxf(a1.z + b1.z, 0.0f), v7 = fmaxf(a1.w + b1.w, 0.0f);
                uint4 H, L;
                split_pack2(v0, v1, H.x, L.x);
                split_pack2(v2, v3, H.y, L.y);
                split_pack2(v4, v5, H.z, L.z);
                split_pack2(v6, v7, H.w, L.w);
                aH[ng][kc] = __builtin_bit_cast(bf16x8, H);
                aL[ng][kc] = __builtin_bit_cast(bf16x8, L);
            }
        }
        // issue next pair's gather NOW; lands during this pair's MFMA phase
        if (p == 0) {
#pragma unroll
            for (int ng = 0; ng < 2; ++ng) {
                const int c = col[(node0 + 2 + ng) * KNB + m];
                const float* br = B3 + (size_t)c * 128 + q * 8;
#pragma unroll
                for (int kc = 0; kc < 4; ++kc) {
                    braw[ng * 8 + kc * 2]     = *(const float4*)(br + kc * 32);
                    braw[ng * 8 + kc * 2 + 1] = *(const float4*)(br + kc * 32 + 4);
                }
            }
        }
        // MFMA: all 8 n-tiles for both nodes; bh/bl amortized over 6 MFMAs
        floatx4 acc[2][8];
#pragma unroll
        for (int ng = 0; ng < 2; ++ng)
#pragma unroll
            for (int nt = 0; nt < 8; ++nt)
                acc[ng][nt] = (floatx4){0.0f, 0.0f, 0.0f, 0.0f};
#pragma unroll
        for (int kc = 0; kc < 4; ++kc) {
#pragma unroll
            for (int nt = 0; nt < 8; ++nt) {
                const int f = kc * 8 + nt;
                bf16x8 bh = __builtin_bit_cast(bf16x8,
                    *(const uint4*)(wlds + f * 512 + lane * 8));
                bf16x8 bl = __builtin_bit_cast(bf16x8,
                    *(const uint4*)(wlds + 16384 + f * 512 + lane * 8));
#pragma unroll
                for (int ng = 0; ng < 2; ++ng) {
                    acc[ng][nt] = __builtin_amdgcn_mfma_f32_16x16x32_bf16(
                        aH[ng][kc], bh, acc[ng][nt], 0, 0, 0);
                    acc[ng][nt] = __builtin_amdgcn_mfma_f32_16x16x32_bf16(
                        aH[ng][kc], bl, acc[ng][nt], 0, 0, 0);
                    acc[ng][nt] = __builtin_amdgcn_mfma_f32_16x16x32_bf16(
                        aL[ng][kc], bh, acc[ng][nt], 0, 0, 0);
                }
            }
        }
        // K-max in-register; g = relu(max + b4) -> gshare (A-frag layout, no
        // register bridge across iterations)
#pragma unroll
        for (int ng = 0; ng < 2; ++ng) {
            const int mloc = w * 4 + p * 2 + ng;
#pragma unroll
            for (int nt = 0; nt < 8; ++nt) {
                floatx4 a = acc[ng][nt];
                float mm = fmaxf(fmaxf(a[0], a[1]), fmaxf(a[2], a[3]));
                mm = fmaxf(mm, __shfl_xor(mm, 16));
                mm = fmaxf(mm, __shfl_xor(mm, 32));
                if (lane < 16) {
                    int colI = nt * 16 + lane;
                    int kc2 = colI >> 5, q2 = (colI >> 3) & 3, jj = colI & 7;
                    gshare[kc2 * 512 + q2 * 128 + mloc * 8 + jj] =
                        fmaxf(mm + b4[colI], 0.0f);
                }
            }
        }
    }

    // ---- fused node MLP: out = relu(g@W5+b5) @ W6 + b6 ----
    __syncthreads();     // gshare complete; ashare A3 reads done
    // W5 GEMM: wave w -> nt {2w, 2w+1}; W5 frags streamed from L2
    floatx4 acc5[2];
    acc5[0] = (floatx4){0.f, 0.f, 0.f, 0.f};
    acc5[1] = (floatx4){0.f, 0.f, 0.f, 0.f};
#pragma unroll
    for (int kc = 0; kc < 4; ++kc) {
        const float* ap = gshare + kc * 512 + lane * 8;
        bf16x8 ah, al;
        split8(*(const float4*)ap, *(const float4*)(ap + 4), ah, al);
#pragma unroll
        for (int ntl = 0; ntl < 2; ++ntl) {
            int nt = w * 2 + ntl;
            size_t fb = (size_t)(W5F + kc * 8 + nt) * 512 + lane * 8;
            bf16x8 bh = __builtin_bit_cast(bf16x8, *(const uint4*)(WH + fb));
            bf16x8 bl = __builtin_bit_cast(bf16x8, *(const uint4*)(WL + fb));
            acc5[ntl] = __builtin_amdgcn_mfma_f32_16x16x32_bf16(ah, bh, acc5[ntl], 0, 0, 0);
            acc5[ntl] = __builtin_amdgcn_mfma_f32_16x16x32_bf16(ah, bl, acc5[ntl], 0, 0, 0);
            acc5[ntl] = __builtin_amdgcn_mfma_f32_16x16x32_bf16(al, bh, acc5[ntl], 0, 0, 0);
        }
    }
    {   // t1 = relu(acc5 + b5) -> ashare frag kc=w (wave-exclusive region)
        const int qq = lane >> 4, cc = lane & 15;
#pragma unroll
        for (int ntl = 0; ntl < 2; ++ntl) {
            int nt = w * 2 + ntl;
            float bv = b5[nt * 16 + cc];
            int colI = nt * 16 + cc;
            int kc2 = colI >> 5, q2 = (colI >> 3) & 3, jj = cc & 7;
            float* dst = ashare + kc2 * 512 + q2 * 128 + jj;
#pragma unroll
            for (int r = 0; r < 4; ++r)
                dst[(qq * 4 + r) * 8] = fmaxf(acc5[ntl][r] + bv, 0.0f);
        }
    }
    __syncthreads();     // t1 complete across waves
    // W6 GEMM: waves 0..2, nt = w; store out
    if (w < 3) {
        floatx4 acc6 = (floatx4){0.f, 0.f, 0.f, 0.f};
#pragma unroll
        for (int kc = 0; kc < 4; ++kc) {
            const float* ap = ashare + kc * 512 + lane * 8;
            bf16x8 ah, al;
            split8(*(const float4*)ap, *(const float4*)(ap + 4), ah, al);
            size_t fb = (size_t)(W6F + kc * 3 + w) * 512 + lane * 8;
            bf16x8 bh = __builtin_bit_cast(bf16x8, *(const uint4*)(WH + fb));
            bf16x8 bl = __builtin_bit_cast(bf16x8, *(const uint4*)(WL + fb));
            acc6 = __builtin_amdgcn_mfma_f32_16x16x32_bf16(ah, bh, acc6, 0, 0, 0);
            acc6 = __builtin_amdgcn_mfma_f32_16x16x32_bf16(ah, bl, acc6, 0, 0, 0);
            acc6 = __builtin_amdgcn_mfma_f32_16x16x32_bf16(al, bh, acc6, 0, 0, 0);
        }
        const int qq = lane >> 4, cc = lane & 15;
        int n = w * 16 + cc;
        if (n < 40) {
            float bv = b6[n];
#pragma unroll
            for (int r = 0; r < 4; ++r)
                out[(size_t)(nodeB + qq * 4 + r) * 40 + n] = acc6[r] + bv;
        }
    }
}

extern "C" void kernel_launch(void* const* d_in, const int* in_sizes, int n_in,
                              void* d_out, int out_size, void* d_ws, size_t ws_size,
                              hipStream_t stream)
{
    const float* x  = (const float*)d_in[0];
    const int* ei   = (const int*)d_in[1];
    const int* col  = ei + EE;
    const float* W1 = (const float*)d_in[2];
    const float* b1 = (const float*)d_in[3];
    const float* W2 = (const float*)d_in[4];
    const float* b2 = (const float*)d_in[5];
    const float* W3 = (const float*)d_in[6];
    const float* b3 = (const float*)d_in[7];
    const float* W4 = (const float*)d_in[8];
    const float* b4 = (const float*)d_in[9];
    const float* W5 = (const float*)d_in[10];
    const float* b5 = (const float*)d_in[11];
    const float* W6 = (const float*)d_in[12];
    const float* b6 = (const float*)d_in[13];
    float* out = (float*)d_out;

    float* A1 = (float*)d_ws;                    // [N,64]
    float* B1 = A1 + (size_t)NN * 64;            // [N,64]
    float* A3 = B1 + (size_t)NN * 64;            // [N,128]
    float* B3 = A3 + (size_t)NN * 128;           // [N,128]
    unsigned short* WH = (unsigned short*)(B3 + (size_t)NN * 128);  // [116*512]
    unsigned short* WL = WH + NFRAG * 512;

    kw_kernel<<<(NFRAG * 64 + 255) / 256, 256, 0, stream>>>(W2, W3, W4, W5, W6, WH, WL);
    k1_kernel<<<NN * 64 / 256, 256, 0, stream>>>(x, W1, b1, A1, B1);
    k2_kernel<<<(NN + 63) / 64, 256, 0, stream>>>(col, A1, B1, WH, WL, b2, b3, A3, B3);
    k3_kernel<<<NN / 16, 256, 0, stream>>>(col, A3, B3, WH, WL, b4, b5, b6, out);
}